// Round 5
// baseline (360.342 us; speedup 1.0000x reference)
//
#include <hip/hip_runtime.h>

#define D_MODEL 1024
#define SEQ 2048
#define BATCH 2
#define NH 16
#define DH 64
#define WIN 128
#define DFF 3072

typedef __bf16 bf16x8 __attribute__((ext_vector_type(8)));
typedef float f32x4 __attribute__((ext_vector_type(4)));
typedef unsigned short u16;
typedef unsigned int u32;

__device__ __forceinline__ float b2f(u16 u) {
    unsigned int x = ((unsigned int)u) << 16;
    return __uint_as_float(x);
}
__device__ __forceinline__ u16 f2b(float f) {
    unsigned int x = __float_as_uint(f);
    x += 0x7fffu + ((x >> 16) & 1u);
    return (u16)(x >> 16);
}
__device__ __forceinline__ u32 pk2(float a, float b) {
    return (u32)f2b(a) | ((u32)f2b(b) << 16);
}

// ------------------------------------------------- transpose + f32->bf16 cvt
__global__ __launch_bounds__(256) void transpose_cvt_k(
        const float* __restrict__ in, u16* __restrict__ out, int R, int C) {
    __shared__ u16 tile[32][33];
    int tx = threadIdx.x & 31;
    int ty = threadIdx.x >> 5;
    int r0 = blockIdx.y * 32, c0 = blockIdx.x * 32;
#pragma unroll
    for (int i = 0; i < 4; ++i)
        tile[ty + i * 8][tx] = f2b(in[(size_t)(r0 + ty + i * 8) * C + c0 + tx]);
    __syncthreads();
#pragma unroll
    for (int i = 0; i < 4; ++i)
        out[(size_t)(c0 + ty + i * 8) * R + r0 + tx] = tile[tx][ty + i * 8];
}

// ---------------------------------------------------------------- layernorm
__global__ __launch_bounds__(256) void ln_k(
        const float* __restrict__ x, const float* __restrict__ g,
        const float* __restrict__ bta, u16* __restrict__ out) {
    int row = blockIdx.x;
    const float* xr = x + (size_t)row * D_MODEL;
    float v[4];
    float sum = 0.f, sq = 0.f;
#pragma unroll
    for (int i = 0; i < 4; ++i) {
        v[i] = xr[threadIdx.x + i * 256];
        sum += v[i];
        sq += v[i] * v[i];
    }
#pragma unroll
    for (int off = 32; off > 0; off >>= 1) {
        sum += __shfl_xor(sum, off, 64);
        sq  += __shfl_xor(sq, off, 64);
    }
    __shared__ float s1[4], s2[4];
    int w = threadIdx.x >> 6;
    if ((threadIdx.x & 63) == 0) { s1[w] = sum; s2[w] = sq; }
    __syncthreads();
    sum = s1[0] + s1[1] + s1[2] + s1[3];
    sq  = s2[0] + s2[1] + s2[2] + s2[3];
    float mu = sum * (1.f / D_MODEL);
    float var = sq * (1.f / D_MODEL) - mu * mu;
    float rstd = rsqrtf(var + 1e-5f);
    u16* outr = out + (size_t)row * D_MODEL;
#pragma unroll
    for (int i = 0; i < 4; ++i) {
        int c = threadIdx.x + i * 256;
        outr[c] = f2b((v[i] - mu) * rstd * g[c] + bta[c]);
    }
}

// ------------------------------------------------------- bias-add broadcast
// dst[i] = src[i] + bias[i % 1024]   (f32, vectorized x4)
__global__ __launch_bounds__(256) void add_bias_k(
        float* __restrict__ dst, const float* __restrict__ src,
        const float* __restrict__ bias) {
    int i = (blockIdx.x * 256 + threadIdx.x) * 4;
    float4 s = *(const float4*)(src + i);
    float4 b = *(const float4*)(bias + (i & (D_MODEL - 1)));
    s.x += b.x; s.y += b.y; s.z += b.z; s.w += b.w;
    *(float4*)(dst + i) = s;
}

// ---------------------------------------------------------------- GEMM
// m97-style: 128x128 tile, 4 waves (2x2), 64x64/wave, BK=32,
// global_load_lds width=16, XOR-swizzled LDS (conflict-free, verified R4).
// Ksub = K this block reduces; lda = row stride of A/Bt; koff = z*Ksub.
// ATOMIC: epilogue does f32 atomicAdd into Cv (split-K); bias/resid/gelu off.
// VSPLIT (QKV): cols >= 2048 (V) written transposed to vt[bh][d][s];
//               Q,K cols written to Cv with row stride ldc (=2048, compact).
template <int GELU, int RESID, int OUTF32, int VSPLIT, int ATOMIC>
__global__ __launch_bounds__(256) void gemm_k(
        const u16* __restrict__ A, const u16* __restrict__ Bt,
        const float* __restrict__ bias, const float* __restrict__ resid,
        void* __restrict__ Cv, u16* __restrict__ vt,
        int M, int N, int Ksub, int lda, int ldc) {
    __shared__ u16 As[128 * 32];
    __shared__ u16 Bs[128 * 32];
    int tid = threadIdx.x;
    int w = tid >> 6, lane = tid & 63;
    int qd = lane >> 4, l15 = lane & 15;
    int m0 = blockIdx.y * 128, n0 = blockIdx.x * 128;
    int koff = blockIdx.z * Ksub;

    const u16* gsrc[4];
    u16* ldst[4];
#pragma unroll
    for (int i = 0; i < 4; ++i) {
        int c = w * 4 + i;
        int cb = c & 7;
        int srow = cb * 16 + (lane >> 2);
        int scol = ((lane & 3) ^ ((srow >> 1) & 3)) * 8;   // XOR swizzle
        gsrc[i] = (c < 8 ? A + (size_t)(m0 + srow) * lda
                         : Bt + (size_t)(n0 + srow) * lda) + koff + scol;
        ldst[i] = (c < 8 ? As : Bs) + cb * 512;
    }

    int wm = w & 1, wn = w >> 1;
    f32x4 acc[4][4];
#pragma unroll
    for (int mt = 0; mt < 4; ++mt)
#pragma unroll
        for (int nt = 0; nt < 4; ++nt)
            acc[mt][nt] = (f32x4){0.f, 0.f, 0.f, 0.f};

    int aoff[4], boff[4];
#pragma unroll
    for (int t = 0; t < 4; ++t) {
        int ar = wm * 64 + t * 16 + l15;
        aoff[t] = ar * 32 + ((qd ^ ((ar >> 1) & 3)) * 8);
        int br = wn * 64 + t * 16 + l15;
        boff[t] = br * 32 + ((qd ^ ((br >> 1) & 3)) * 8);
    }

    for (int k0 = 0; k0 < Ksub; k0 += 32) {
        __syncthreads();
#pragma unroll
        for (int i = 0; i < 4; ++i)
            __builtin_amdgcn_global_load_lds(
                (__attribute__((address_space(1))) void*)(gsrc[i] + k0),
                (__attribute__((address_space(3))) void*)(ldst[i]), 16, 0, 0);
        __syncthreads();
        bf16x8 av[4], bv[4];
#pragma unroll
        for (int t = 0; t < 4; ++t) {
            av[t] = *(const bf16x8*)&As[aoff[t]];
            bv[t] = *(const bf16x8*)&Bs[boff[t]];
        }
#pragma unroll
        for (int mt = 0; mt < 4; ++mt)
#pragma unroll
            for (int nt = 0; nt < 4; ++nt)
                acc[mt][nt] = __builtin_amdgcn_mfma_f32_16x16x32_bf16(
                    av[mt], bv[nt], acc[mt][nt], 0, 0, 0);
    }

#pragma unroll
    for (int mt = 0; mt < 4; ++mt) {
        int row0 = m0 + wm * 64 + mt * 16 + qd * 4;
#pragma unroll
        for (int nt = 0; nt < 4; ++nt) {
            int col = n0 + wn * 64 + nt * 16 + l15;
            if (ATOMIC) {
#pragma unroll
                for (int reg = 0; reg < 4; ++reg)
                    unsafeAtomicAdd(&((float*)Cv)[(size_t)(row0 + reg) * ldc + col],
                                    acc[mt][nt][reg]);
                continue;
            }
            float v[4];
#pragma unroll
            for (int reg = 0; reg < 4; ++reg) {
                v[reg] = acc[mt][nt][reg] + bias[col];
                if (GELU) v[reg] = 0.5f * v[reg] * (1.f + erff(v[reg] * 0.70710678118654752f));
                if (RESID) v[reg] += resid[(size_t)(row0 + reg) * ldc + col];
            }
            if (VSPLIT && col >= 2 * D_MODEL) {
                int d = col - 2 * D_MODEL;
                int bh = (row0 >> 11) * NH + (d >> 6);
                ushort4 pkv = {f2b(v[0]), f2b(v[1]), f2b(v[2]), f2b(v[3])};
                *(ushort4*)&vt[((size_t)(bh * DH + (d & 63))) * SEQ + (row0 & (SEQ - 1))] = pkv;
            } else {
#pragma unroll
                for (int reg = 0; reg < 4; ++reg) {
                    if (OUTF32) ((float*)Cv)[(size_t)(row0 + reg) * ldc + col] = v[reg];
                    else        ((u16*)Cv)[(size_t)(row0 + reg) * ldc + col] = f2b(v[reg]);
                }
            }
        }
    }
}

// ---------------------------------------------------------------- attention
// Flash-style MFMA; one wave per 16-query tile; <=5 chunks of 32 keys.
// qk buffer layout (bf16): [b, s, {q:0..1023, k:1024..2047}]
__global__ __launch_bounds__(256) void attn_k(
        const u16* __restrict__ qk, const u16* __restrict__ vt,
        u16* __restrict__ ctx) {
    int lane = threadIdx.x & 63, l15 = lane & 15, quad = lane >> 4;
    int t = blockIdx.x * 4 + (threadIdx.x >> 6);
    int qt = t & (SEQ / 16 - 1);
    int h  = (t >> 7) & (NH - 1);
    int b  = t >> 11;
    int q0 = qt * 16;
    int bh = b * NH + h;

    const u16* qrow = qk + (size_t)(b * SEQ + q0 + l15) * (2 * D_MODEL) + h * DH + quad * 8;
    bf16x8 qf0 = *(const bf16x8*)(qrow);
    bf16x8 qf1 = *(const bf16x8*)(qrow + 32);
    const u16* kbase = qk + (size_t)(b * SEQ) * (2 * D_MODEL) + D_MODEL + h * DH + quad * 8;
    const u16* vbase = vt + (size_t)(bh * DH) * SEQ;

    f32x4 o[4] = {{0.f, 0.f, 0.f, 0.f}, {0.f, 0.f, 0.f, 0.f},
                  {0.f, 0.f, 0.f, 0.f}, {0.f, 0.f, 0.f, 0.f}};
    float m = -1e30f, l = 0.f;
    int q = q0 + l15;
    int cs = q0 - (WIN - 1);
    cs = cs < 0 ? 0 : (cs & ~31);

    for (int c = cs; c <= q0 + 15; c += 32) {
        const u16* k0p = kbase + (size_t)(c + l15) * (2 * D_MODEL);
        const u16* k1p = k0p + (size_t)16 * (2 * D_MODEL);
        bf16x8 ka0 = *(const bf16x8*)(k0p);
        bf16x8 ka1 = *(const bf16x8*)(k0p + 32);
        bf16x8 kb0 = *(const bf16x8*)(k1p);
        bf16x8 kb1 = *(const bf16x8*)(k1p + 32);
        f32x4 s0 = {0.f, 0.f, 0.f, 0.f}, s1 = {0.f, 0.f, 0.f, 0.f};
        s0 = __builtin_amdgcn_mfma_f32_16x16x32_bf16(ka0, qf0, s0, 0, 0, 0);
        s0 = __builtin_amdgcn_mfma_f32_16x16x32_bf16(ka1, qf1, s0, 0, 0, 0);
        s1 = __builtin_amdgcn_mfma_f32_16x16x32_bf16(kb0, qf0, s1, 0, 0, 0);
        s1 = __builtin_amdgcn_mfma_f32_16x16x32_bf16(kb1, qf1, s1, 0, 0, 0);

        float p0[4], p1[4];
        float cm = -1e30f;
#pragma unroll
        for (int reg = 0; reg < 4; ++reg) {
            int k0i = c + quad * 4 + reg;
            p0[reg] = ((unsigned)(q - k0i) < WIN) ? s0[reg] * 0.125f : -1e30f;
            p1[reg] = ((unsigned)(q - k0i - 16) < WIN) ? s1[reg] * 0.125f : -1e30f;
            cm = fmaxf(cm, fmaxf(p0[reg], p1[reg]));
        }
        cm = fmaxf(cm, __shfl_xor(cm, 16, 64));
        cm = fmaxf(cm, __shfl_xor(cm, 32, 64));
        float mn = fmaxf(m, cm);
        float alpha = __expf(m - mn);
        m = mn;
        float ls = 0.f;
#pragma unroll
        for (int reg = 0; reg < 4; ++reg) {
            p0[reg] = __expf(p0[reg] - mn);
            p1[reg] = __expf(p1[reg] - mn);
            ls += p0[reg] + p1[reg];
        }
        ls += __shfl_xor(ls, 16, 64);
        ls += __shfl_xor(ls, 32, 64);
        l = l * alpha + ls;
#pragma unroll
        for (int mt = 0; mt < 4; ++mt) o[mt] *= alpha;

        u32 z0 = pk2(p0[0], p0[1]), z1 = pk2(p0[2], p0[3]);
        u32 w0 = pk2(p1[0], p1[1]), w1 = pk2(p1[2], p1[3]);
        int slo = ((quad & 1) * 2) * 16 + l15;
        int shi = slo + 16;
        u32 zl0 = (u32)__shfl((int)z0, slo, 64), zl1 = (u32)__shfl((int)z1, slo, 64);
        u32 zh0 = (u32)__shfl((int)z0, shi, 64), zh1 = (u32)__shfl((int)z1, shi, 64);
        u32 wl0 = (u32)__shfl((int)w0, slo, 64), wl1 = (u32)__shfl((int)w1, slo, 64);
        u32 wh0 = (u32)__shfl((int)w0, shi, 64), wh1 = (u32)__shfl((int)w1, shi, 64);
        alignas(16) u32 pr[4];
        pr[0] = quad < 2 ? zl0 : wl0;
        pr[1] = quad < 2 ? zl1 : wl1;
        pr[2] = quad < 2 ? zh0 : wh0;
        pr[3] = quad < 2 ? zh1 : wh1;
        bf16x8 pf = *(const bf16x8*)pr;

#pragma unroll
        for (int mt = 0; mt < 4; ++mt) {
            bf16x8 vf = *(const bf16x8*)(vbase + (size_t)(mt * 16 + l15) * SEQ + c + quad * 8);
            o[mt] = __builtin_amdgcn_mfma_f32_16x16x32_bf16(vf, pf, o[mt], 0, 0, 0);
        }
    }

    float rdiv = 1.f / l;
    u16* crow = ctx + (size_t)(b * SEQ + q0 + l15) * D_MODEL + h * DH;
#pragma unroll
    for (int mt = 0; mt < 4; ++mt) {
        ushort4 pkv = {f2b(o[mt][0] * rdiv), f2b(o[mt][1] * rdiv),
                       f2b(o[mt][2] * rdiv), f2b(o[mt][3] * rdiv)};
        *(ushort4*)(crow + mt * 16 + quad * 4) = pkv;
    }
}

// ---------------------------------------------------------------- launch
extern "C" void kernel_launch(void* const* d_in, const int* in_sizes, int n_in,
                              void* d_out, int out_size, void* d_ws, size_t ws_size,
                              hipStream_t stream) {
    (void)in_sizes; (void)n_in; (void)out_size; (void)ws_size;
    const float* x     = (const float*)d_in[0];
    const float* w_qkv = (const float*)d_in[1];
    const float* b_qkv = (const float*)d_in[2];
    const float* w_out = (const float*)d_in[3];
    const float* b_out = (const float*)d_in[4];
    const float* w_ff1 = (const float*)d_in[5];
    const float* b_ff1 = (const float*)d_in[6];
    const float* w_ff2 = (const float*)d_in[7];
    const float* b_ff2 = (const float*)d_in[8];
    const float* ln1g  = (const float*)d_in[9];
    const float* ln1b  = (const float*)d_in[10];
    const float* ln2g  = (const float*)d_in[11];
    const float* ln2b  = (const float*)d_in[12];
    float* out = (float*)d_out;

    const int M = BATCH * SEQ;                       // 4096
    char* base = (char*)d_ws;                        // 76 MiB peak (proven)
    u16*   hbf   = (u16*)(base);                     //  8 MiB: LN out
    u16*   qkbuf = (u16*)(base + (8ll  << 20));      // 16 MiB: Q,K [b,s,2048]
    u16*   ctxbf = (u16*)(base + (24ll << 20));      //  8 MiB: attn out
    u16*   vtbuf = (u16*)(base + (32ll << 20));      //  8 MiB: V^T [bh][d][s]
    u16*   ffbf  = (u16*)(base + (8ll  << 20));      // 24 MiB: FF inter (overlays qk+ctx; disjoint lifetime)
    float* x2    = (float*)(base + (40ll << 20));    // 16 MiB: f32 residual
    u16*   wqkvT = (u16*)(base + (56ll << 20));      //  6 MiB
    u16*   woutT = (u16*)(base + (62ll << 20));      //  2 MiB
    u16*   wff1T = (u16*)(base + (64ll << 20));      //  6 MiB
    u16*   wff2T = (u16*)(base + (70ll << 20));      //  6 MiB

    transpose_cvt_k<<<dim3(3 * D_MODEL / 32, D_MODEL / 32), 256, 0, stream>>>(w_qkv, wqkvT, D_MODEL, 3 * D_MODEL);
    transpose_cvt_k<<<dim3(D_MODEL / 32, D_MODEL / 32), 256, 0, stream>>>(w_out, woutT, D_MODEL, D_MODEL);
    transpose_cvt_k<<<dim3(DFF / 32, D_MODEL / 32), 256, 0, stream>>>(w_ff1, wff1T, D_MODEL, DFF);
    transpose_cvt_k<<<dim3(D_MODEL / 32, DFF / 32), 256, 0, stream>>>(w_ff2, wff2T, DFF, D_MODEL);

    // hbf = bf16(LN1(x))
    ln_k<<<M, 256, 0, stream>>>(x, ln1g, ln1b, hbf);
    // QKV: Q,K -> qkbuf (ld 2048); V -> vtbuf transposed
    gemm_k<0, 0, 0, 1, 0><<<dim3(3 * D_MODEL / 128, M / 128), 256, 0, stream>>>(
        hbf, wqkvT, b_qkv, nullptr, qkbuf, vtbuf, M, 3 * D_MODEL, D_MODEL, D_MODEL, 2 * D_MODEL);
    attn_k<<<dim3(BATCH * NH * (SEQ / 16) / 4), 256, 0, stream>>>(qkbuf, vtbuf, ctxbf);
    // x2 = x + b_out, then split-K=2 atomic accumulate ctx @ w_out
    add_bias_k<<<M * D_MODEL / 1024, 256, 0, stream>>>(x2, x, b_out);
    gemm_k<0, 0, 0, 0, 1><<<dim3(D_MODEL / 128, M / 128, 2), 256, 0, stream>>>(
        ctxbf, woutT, nullptr, nullptr, x2, nullptr, M, D_MODEL, D_MODEL / 2, D_MODEL, D_MODEL);
    // hbf = bf16(LN2(x2))
    ln_k<<<M, 256, 0, stream>>>(x2, ln2g, ln2b, hbf);
    // ffbf = bf16(gelu(hbf @ w_ff1 + b_ff1))
    gemm_k<1, 0, 0, 0, 0><<<dim3(DFF / 128, M / 128), 256, 0, stream>>>(
        hbf, wff1T, b_ff1, nullptr, ffbf, nullptr, M, DFF, D_MODEL, D_MODEL, DFF);
    // out = x2 + b_ff2, then split-K=3 atomic accumulate ff @ w_ff2
    add_bias_k<<<M * D_MODEL / 1024, 256, 0, stream>>>(out, x2, b_ff2);
    gemm_k<0, 0, 0, 0, 1><<<dim3(D_MODEL / 128, M / 128, 3), 256, 0, stream>>>(
        ffbf, wff2T, nullptr, nullptr, out, nullptr, M, D_MODEL, DFF / 3, DFF, D_MODEL);
}

// Round 6
// 314.910 us; speedup vs baseline: 1.1443x; 1.1443x over previous
//
#include <hip/hip_runtime.h>

#define D_MODEL 1024
#define SEQ 2048
#define BATCH 2
#define NH 16
#define DH 64
#define WIN 128
#define DFF 3072

typedef __bf16 bf16x8 __attribute__((ext_vector_type(8)));
typedef float f32x4 __attribute__((ext_vector_type(4)));
typedef unsigned short u16;
typedef unsigned int u32;

__device__ __forceinline__ float b2f(u16 u) {
    unsigned int x = ((unsigned int)u) << 16;
    return __uint_as_float(x);
}
__device__ __forceinline__ u16 f2b(float f) {
    unsigned int x = __float_as_uint(f);
    x += 0x7fffu + ((x >> 16) & 1u);
    return (u16)(x >> 16);
}
__device__ __forceinline__ u32 pk2(float a, float b) {
    return (u32)f2b(a) | ((u32)f2b(b) << 16);
}

// ------------------------------------------------- transpose + f32->bf16 cvt
__global__ __launch_bounds__(256) void transpose_cvt_k(
        const float* __restrict__ in, u16* __restrict__ out, int R, int C) {
    __shared__ u16 tile[32][33];
    int tx = threadIdx.x & 31;
    int ty = threadIdx.x >> 5;
    int r0 = blockIdx.y * 32, c0 = blockIdx.x * 32;
#pragma unroll
    for (int i = 0; i < 4; ++i)
        tile[ty + i * 8][tx] = f2b(in[(size_t)(r0 + ty + i * 8) * C + c0 + tx]);
    __syncthreads();
#pragma unroll
    for (int i = 0; i < 4; ++i)
        out[(size_t)(c0 + ty + i * 8) * R + r0 + tx] = tile[tx][ty + i * 8];
}

// ---------------------------------------------------------------- layernorm
__global__ __launch_bounds__(256) void ln_k(
        const float* __restrict__ x, const float* __restrict__ g,
        const float* __restrict__ bta, u16* __restrict__ out) {
    int row = blockIdx.x;
    const float* xr = x + (size_t)row * D_MODEL;
    float v[4];
    float sum = 0.f, sq = 0.f;
#pragma unroll
    for (int i = 0; i < 4; ++i) {
        v[i] = xr[threadIdx.x + i * 256];
        sum += v[i];
        sq += v[i] * v[i];
    }
#pragma unroll
    for (int off = 32; off > 0; off >>= 1) {
        sum += __shfl_xor(sum, off, 64);
        sq  += __shfl_xor(sq, off, 64);
    }
    __shared__ float s1[4], s2[4];
    int w = threadIdx.x >> 6;
    if ((threadIdx.x & 63) == 0) { s1[w] = sum; s2[w] = sq; }
    __syncthreads();
    sum = s1[0] + s1[1] + s1[2] + s1[3];
    sq  = s2[0] + s2[1] + s2[2] + s2[3];
    float mu = sum * (1.f / D_MODEL);
    float var = sq * (1.f / D_MODEL) - mu * mu;
    float rstd = rsqrtf(var + 1e-5f);
    u16* outr = out + (size_t)row * D_MODEL;
#pragma unroll
    for (int i = 0; i < 4; ++i) {
        int c = threadIdx.x + i * 256;
        outr[c] = f2b((v[i] - mu) * rstd * g[c] + bta[c]);
    }
}

// ---------------------------------------------------------------- GEMM
// 128x128 tile, 4 waves (2x2), 64x64/wave, BK=64, global_load_lds width=16.
// 1D grid with XCD swizzle: lin&7 = XCD, each XCD owns a 512-row A-stripe
// (y = xcd*4 + idx%4, x = idx/4) so A re-reads hit that XCD's 4 MiB L2.
// XOR swizzle (global-side, since global_load_lds forces LDS slot = lane):
// LDS slot s of an 8-row chunk holds global col-group s ^ (row&7); reads
// compensate -> 2-way bank aliasing max (free, m136).
template <int GELU, int RESID, int OUTF32, int VSPLIT>
__global__ __launch_bounds__(256) void gemm_k(
        const u16* __restrict__ A, const u16* __restrict__ Bt,
        const float* __restrict__ bias, const float* __restrict__ resid,
        void* __restrict__ Cv, u16* __restrict__ vt,
        int M, int N, int K, int ldc) {
    __shared__ u16 As[128 * 64];
    __shared__ u16 Bs[128 * 64];
    int tid = threadIdx.x;
    int w = tid >> 6, lane = tid & 63;
    int qd = lane >> 4, l15 = lane & 15;

    int lin = blockIdx.x;
    int xcd = lin & 7, idx = lin >> 3;
    int m0 = (xcd * 4 + (idx & 3)) * 128;      // y: XCD-local A stripe
    int n0 = (idx >> 2) * 128;                 // x

    // Staging: 32 chunks of 1 KiB (8 rows x 64 cols bf16); wave w owns 8.
    const u16* gsrc[8];
    u16* ldst[8];
#pragma unroll
    for (int i = 0; i < 8; ++i) {
        int c = w * 8 + i;                     // 0..31; 0-15 = A, 16-31 = B
        int cb = c & 15;
        int row = cb * 8 + (lane >> 3);
        int cg = (lane & 7) ^ (row & 7);       // XOR swizzle, global side
        gsrc[i] = (c < 16 ? A + (size_t)(m0 + row) * K
                          : Bt + (size_t)(n0 + row) * K) + cg * 8;
        ldst[i] = (c < 16 ? As : Bs) + cb * 512;
    }

    int wm = w & 1, wn = w >> 1;
    f32x4 acc[4][4];
#pragma unroll
    for (int mt = 0; mt < 4; ++mt)
#pragma unroll
        for (int nt = 0; nt < 4; ++nt)
            acc[mt][nt] = (f32x4){0.f, 0.f, 0.f, 0.f};

    int aoff[4][2], boff[4][2];
#pragma unroll
    for (int t = 0; t < 4; ++t) {
        int ar = wm * 64 + t * 16 + l15;
        int br = wn * 64 + t * 16 + l15;
#pragma unroll
        for (int h = 0; h < 2; ++h) {
            aoff[t][h] = ar * 64 + (((h * 4 + qd) ^ (ar & 7)) * 8);
            boff[t][h] = br * 64 + (((h * 4 + qd) ^ (br & 7)) * 8);
        }
    }

    for (int k0 = 0; k0 < K; k0 += 64) {
        __syncthreads();
#pragma unroll
        for (int i = 0; i < 8; ++i)
            __builtin_amdgcn_global_load_lds(
                (__attribute__((address_space(1))) void*)(gsrc[i] + k0),
                (__attribute__((address_space(3))) void*)(ldst[i]), 16, 0, 0);
        __syncthreads();
        bf16x8 av[4][2], bv[4][2];
#pragma unroll
        for (int t = 0; t < 4; ++t)
#pragma unroll
            for (int h = 0; h < 2; ++h) {
                av[t][h] = *(const bf16x8*)&As[aoff[t][h]];
                bv[t][h] = *(const bf16x8*)&Bs[boff[t][h]];
            }
#pragma unroll
        for (int mt = 0; mt < 4; ++mt)
#pragma unroll
            for (int nt = 0; nt < 4; ++nt) {
                acc[mt][nt] = __builtin_amdgcn_mfma_f32_16x16x32_bf16(
                    av[mt][0], bv[nt][0], acc[mt][nt], 0, 0, 0);
                acc[mt][nt] = __builtin_amdgcn_mfma_f32_16x16x32_bf16(
                    av[mt][1], bv[nt][1], acc[mt][nt], 0, 0, 0);
            }
    }

#pragma unroll
    for (int mt = 0; mt < 4; ++mt) {
        int row0 = m0 + wm * 64 + mt * 16 + qd * 4;
#pragma unroll
        for (int nt = 0; nt < 4; ++nt) {
            int col = n0 + wn * 64 + nt * 16 + l15;
            float v[4];
#pragma unroll
            for (int reg = 0; reg < 4; ++reg) {
                v[reg] = acc[mt][nt][reg] + bias[col];
                if (GELU) v[reg] = 0.5f * v[reg] * (1.f + erff(v[reg] * 0.70710678118654752f));
                if (RESID) v[reg] += resid[(size_t)(row0 + reg) * ldc + col];
            }
            if (VSPLIT && col >= 2 * D_MODEL) {
                int d = col - 2 * D_MODEL;
                int bh = (row0 >> 11) * NH + (d >> 6);
                ushort4 pkv = {f2b(v[0]), f2b(v[1]), f2b(v[2]), f2b(v[3])};
                *(ushort4*)&vt[((size_t)(bh * DH + (d & 63))) * SEQ + (row0 & (SEQ - 1))] = pkv;
            } else {
#pragma unroll
                for (int reg = 0; reg < 4; ++reg) {
                    if (OUTF32) ((float*)Cv)[(size_t)(row0 + reg) * ldc + col] = v[reg];
                    else        ((u16*)Cv)[(size_t)(row0 + reg) * ldc + col] = f2b(v[reg]);
                }
            }
        }
    }
}

// ---------------------------------------------------------------- attention
// Flash-style MFMA; one wave per 16-query tile; <=5 chunks of 32 keys.
// qk buffer layout (bf16): [b, s, {q:0..1023, k:1024..2047}]
__global__ __launch_bounds__(256) void attn_k(
        const u16* __restrict__ qk, const u16* __restrict__ vt,
        u16* __restrict__ ctx) {
    int lane = threadIdx.x & 63, l15 = lane & 15, quad = lane >> 4;
    int t = blockIdx.x * 4 + (threadIdx.x >> 6);
    int qt = t & (SEQ / 16 - 1);
    int h  = (t >> 7) & (NH - 1);
    int b  = t >> 11;
    int q0 = qt * 16;
    int bh = b * NH + h;

    const u16* qrow = qk + (size_t)(b * SEQ + q0 + l15) * (2 * D_MODEL) + h * DH + quad * 8;
    bf16x8 qf0 = *(const bf16x8*)(qrow);
    bf16x8 qf1 = *(const bf16x8*)(qrow + 32);
    const u16* kbase = qk + (size_t)(b * SEQ) * (2 * D_MODEL) + D_MODEL + h * DH + quad * 8;
    const u16* vbase = vt + (size_t)(bh * DH) * SEQ;

    f32x4 o[4] = {{0.f, 0.f, 0.f, 0.f}, {0.f, 0.f, 0.f, 0.f},
                  {0.f, 0.f, 0.f, 0.f}, {0.f, 0.f, 0.f, 0.f}};
    float m = -1e30f, l = 0.f;
    int q = q0 + l15;
    int cs = q0 - (WIN - 1);
    cs = cs < 0 ? 0 : (cs & ~31);

    for (int c = cs; c <= q0 + 15; c += 32) {
        const u16* k0p = kbase + (size_t)(c + l15) * (2 * D_MODEL);
        const u16* k1p = k0p + (size_t)16 * (2 * D_MODEL);
        bf16x8 ka0 = *(const bf16x8*)(k0p);
        bf16x8 ka1 = *(const bf16x8*)(k0p + 32);
        bf16x8 kb0 = *(const bf16x8*)(k1p);
        bf16x8 kb1 = *(const bf16x8*)(k1p + 32);
        f32x4 s0 = {0.f, 0.f, 0.f, 0.f}, s1 = {0.f, 0.f, 0.f, 0.f};
        s0 = __builtin_amdgcn_mfma_f32_16x16x32_bf16(ka0, qf0, s0, 0, 0, 0);
        s0 = __builtin_amdgcn_mfma_f32_16x16x32_bf16(ka1, qf1, s0, 0, 0, 0);
        s1 = __builtin_amdgcn_mfma_f32_16x16x32_bf16(kb0, qf0, s1, 0, 0, 0);
        s1 = __builtin_amdgcn_mfma_f32_16x16x32_bf16(kb1, qf1, s1, 0, 0, 0);

        float p0[4], p1[4];
        float cm = -1e30f;
#pragma unroll
        for (int reg = 0; reg < 4; ++reg) {
            int k0i = c + quad * 4 + reg;
            p0[reg] = ((unsigned)(q - k0i) < WIN) ? s0[reg] * 0.125f : -1e30f;
            p1[reg] = ((unsigned)(q - k0i - 16) < WIN) ? s1[reg] * 0.125f : -1e30f;
            cm = fmaxf(cm, fmaxf(p0[reg], p1[reg]));
        }
        cm = fmaxf(cm, __shfl_xor(cm, 16, 64));
        cm = fmaxf(cm, __shfl_xor(cm, 32, 64));
        float mn = fmaxf(m, cm);
        float alpha = __expf(m - mn);
        m = mn;
        float ls = 0.f;
#pragma unroll
        for (int reg = 0; reg < 4; ++reg) {
            p0[reg] = __expf(p0[reg] - mn);
            p1[reg] = __expf(p1[reg] - mn);
            ls += p0[reg] + p1[reg];
        }
        ls += __shfl_xor(ls, 16, 64);
        ls += __shfl_xor(ls, 32, 64);
        l = l * alpha + ls;
#pragma unroll
        for (int mt = 0; mt < 4; ++mt) o[mt] *= alpha;

        u32 z0 = pk2(p0[0], p0[1]), z1 = pk2(p0[2], p0[3]);
        u32 w0 = pk2(p1[0], p1[1]), w1 = pk2(p1[2], p1[3]);
        int slo = ((quad & 1) * 2) * 16 + l15;
        int shi = slo + 16;
        u32 zl0 = (u32)__shfl((int)z0, slo, 64), zl1 = (u32)__shfl((int)z1, slo, 64);
        u32 zh0 = (u32)__shfl((int)z0, shi, 64), zh1 = (u32)__shfl((int)z1, shi, 64);
        u32 wl0 = (u32)__shfl((int)w0, slo, 64), wl1 = (u32)__shfl((int)w1, slo, 64);
        u32 wh0 = (u32)__shfl((int)w0, shi, 64), wh1 = (u32)__shfl((int)w1, shi, 64);
        alignas(16) u32 pr[4];
        pr[0] = quad < 2 ? zl0 : wl0;
        pr[1] = quad < 2 ? zl1 : wl1;
        pr[2] = quad < 2 ? zh0 : wh0;
        pr[3] = quad < 2 ? zh1 : wh1;
        bf16x8 pf = *(const bf16x8*)pr;

#pragma unroll
        for (int mt = 0; mt < 4; ++mt) {
            bf16x8 vf = *(const bf16x8*)(vbase + (size_t)(mt * 16 + l15) * SEQ + c + quad * 8);
            o[mt] = __builtin_amdgcn_mfma_f32_16x16x32_bf16(vf, pf, o[mt], 0, 0, 0);
        }
    }

    float rdiv = 1.f / l;
    u16* crow = ctx + (size_t)(b * SEQ + q0 + l15) * D_MODEL + h * DH;
#pragma unroll
    for (int mt = 0; mt < 4; ++mt) {
        ushort4 pkv = {f2b(o[mt][0] * rdiv), f2b(o[mt][1] * rdiv),
                       f2b(o[mt][2] * rdiv), f2b(o[mt][3] * rdiv)};
        *(ushort4*)(crow + mt * 16 + quad * 4) = pkv;
    }
}

// ---------------------------------------------------------------- launch
extern "C" void kernel_launch(void* const* d_in, const int* in_sizes, int n_in,
                              void* d_out, int out_size, void* d_ws, size_t ws_size,
                              hipStream_t stream) {
    (void)in_sizes; (void)n_in; (void)out_size; (void)ws_size;
    const float* x     = (const float*)d_in[0];
    const float* w_qkv = (const float*)d_in[1];
    const float* b_qkv = (const float*)d_in[2];
    const float* w_out = (const float*)d_in[3];
    const float* b_out = (const float*)d_in[4];
    const float* w_ff1 = (const float*)d_in[5];
    const float* b_ff1 = (const float*)d_in[6];
    const float* w_ff2 = (const float*)d_in[7];
    const float* b_ff2 = (const float*)d_in[8];
    const float* ln1g  = (const float*)d_in[9];
    const float* ln1b  = (const float*)d_in[10];
    const float* ln2g  = (const float*)d_in[11];
    const float* ln2b  = (const float*)d_in[12];
    float* out = (float*)d_out;

    const int M = BATCH * SEQ;                       // 4096
    char* base = (char*)d_ws;                        // 76 MiB peak
    u16*   hbf   = (u16*)(base);                     //  8 MiB: LN out
    u16*   qkbuf = (u16*)(base + (8ll  << 20));      // 16 MiB: Q,K [b,s,2048]
    u16*   ctxbf = (u16*)(base + (24ll << 20));      //  8 MiB: attn out
    u16*   vtbuf = (u16*)(base + (32ll << 20));      //  8 MiB: V^T [bh][d][s]
    u16*   ffbf  = (u16*)(base + (8ll  << 20));      // 24 MiB: FF inter (overlays qk+ctx, disjoint lifetime)
    float* x2    = (float*)(base + (40ll << 20));    // 16 MiB: f32 residual
    u16*   wqkvT = (u16*)(base + (56ll << 20));      //  6 MiB
    u16*   woutT = (u16*)(base + (62ll << 20));      //  2 MiB
    u16*   wff1T = (u16*)(base + (64ll << 20));      //  6 MiB
    u16*   wff2T = (u16*)(base + (70ll << 20));      //  6 MiB

    transpose_cvt_k<<<dim3(3 * D_MODEL / 32, D_MODEL / 32), 256, 0, stream>>>(w_qkv, wqkvT, D_MODEL, 3 * D_MODEL);
    transpose_cvt_k<<<dim3(D_MODEL / 32, D_MODEL / 32), 256, 0, stream>>>(w_out, woutT, D_MODEL, D_MODEL);
    transpose_cvt_k<<<dim3(DFF / 32, D_MODEL / 32), 256, 0, stream>>>(w_ff1, wff1T, D_MODEL, DFF);
    transpose_cvt_k<<<dim3(D_MODEL / 32, DFF / 32), 256, 0, stream>>>(w_ff2, wff2T, DFF, D_MODEL);

    // hbf = bf16(LN1(x))
    ln_k<<<M, 256, 0, stream>>>(x, ln1g, ln1b, hbf);
    // QKV: Q,K -> qkbuf (ldc 2048); V -> vtbuf transposed
    gemm_k<0, 0, 0, 1><<<dim3((3 * D_MODEL / 128) * 32), 256, 0, stream>>>(
        hbf, wqkvT, b_qkv, nullptr, qkbuf, vtbuf, M, 3 * D_MODEL, D_MODEL, 2 * D_MODEL);
    attn_k<<<dim3(BATCH * NH * (SEQ / 16) / 4), 256, 0, stream>>>(qkbuf, vtbuf, ctxbf);
    // x2 = x + ctx @ w_out + b_out
    gemm_k<0, 1, 1, 0><<<dim3((D_MODEL / 128) * 32), 256, 0, stream>>>(
        ctxbf, woutT, b_out, x, x2, nullptr, M, D_MODEL, D_MODEL, D_MODEL);
    // hbf = bf16(LN2(x2))
    ln_k<<<M, 256, 0, stream>>>(x2, ln2g, ln2b, hbf);
    // ffbf = bf16(gelu(hbf @ w_ff1 + b_ff1))
    gemm_k<1, 0, 0, 0><<<dim3((DFF / 128) * 32), 256, 0, stream>>>(
        hbf, wff1T, b_ff1, nullptr, ffbf, nullptr, M, DFF, D_MODEL, DFF);
    // out = x2 + ffbf @ w_ff2 + b_ff2
    gemm_k<0, 1, 1, 0><<<dim3((D_MODEL / 128) * 32), 256, 0, stream>>>(
        ffbf, wff2T, b_ff2, x2, out, nullptr, M, D_MODEL, DFF, D_MODEL);
}

// Round 7
// 285.463 us; speedup vs baseline: 1.2623x; 1.1032x over previous
//
#include <hip/hip_runtime.h>

#define D_MODEL 1024
#define SEQ 2048
#define BATCH 2
#define NH 16
#define DH 64
#define WIN 128
#define DFF 3072

typedef __bf16 bf16x8 __attribute__((ext_vector_type(8)));
typedef float f32x4 __attribute__((ext_vector_type(4)));
typedef unsigned short u16;
typedef unsigned int u32;

__device__ __forceinline__ float b2f(u16 u) {
    unsigned int x = ((unsigned int)u) << 16;
    return __uint_as_float(x);
}
__device__ __forceinline__ u16 f2b(float f) {
    unsigned int x = __float_as_uint(f);
    x += 0x7fffu + ((x >> 16) & 1u);
    return (u16)(x >> 16);
}
__device__ __forceinline__ u32 pk2(float a, float b) {
    return (u32)f2b(a) | ((u32)f2b(b) << 16);
}

// s_waitcnt imm: vmcnt[3:0]|[15:14], exp[6:4], lgkm[11:8]. vmcnt(0), no
// exp/lgkm wait: 0x0F70.
#define WAIT_VMCNT0() __builtin_amdgcn_s_waitcnt(0x0F70)

// ------------------------------------------------- transpose + f32->bf16 cvt
__global__ __launch_bounds__(256) void transpose_cvt_k(
        const float* __restrict__ in, u16* __restrict__ out, int R, int C) {
    __shared__ u16 tile[32][33];
    int tx = threadIdx.x & 31;
    int ty = threadIdx.x >> 5;
    int r0 = blockIdx.y * 32, c0 = blockIdx.x * 32;
#pragma unroll
    for (int i = 0; i < 4; ++i)
        tile[ty + i * 8][tx] = f2b(in[(size_t)(r0 + ty + i * 8) * C + c0 + tx]);
    __syncthreads();
#pragma unroll
    for (int i = 0; i < 4; ++i)
        out[(size_t)(c0 + ty + i * 8) * R + r0 + tx] = tile[tx][ty + i * 8];
}

// ---------------------------------------------------------------- layernorm
__global__ __launch_bounds__(256) void ln_k(
        const float* __restrict__ x, const float* __restrict__ g,
        const float* __restrict__ bta, u16* __restrict__ out) {
    int row = blockIdx.x;
    const float* xr = x + (size_t)row * D_MODEL;
    float v[4];
    float sum = 0.f, sq = 0.f;
#pragma unroll
    for (int i = 0; i < 4; ++i) {
        v[i] = xr[threadIdx.x + i * 256];
        sum += v[i];
        sq += v[i] * v[i];
    }
#pragma unroll
    for (int off = 32; off > 0; off >>= 1) {
        sum += __shfl_xor(sum, off, 64);
        sq  += __shfl_xor(sq, off, 64);
    }
    __shared__ float s1[4], s2[4];
    int w = threadIdx.x >> 6;
    if ((threadIdx.x & 63) == 0) { s1[w] = sum; s2[w] = sq; }
    __syncthreads();
    sum = s1[0] + s1[1] + s1[2] + s1[3];
    sq  = s2[0] + s2[1] + s2[2] + s2[3];
    float mu = sum * (1.f / D_MODEL);
    float var = sq * (1.f / D_MODEL) - mu * mu;
    float rstd = rsqrtf(var + 1e-5f);
    u16* outr = out + (size_t)row * D_MODEL;
#pragma unroll
    for (int i = 0; i < 4; ++i) {
        int c = threadIdx.x + i * 256;
        outr[c] = f2b((v[i] - mu) * rstd * g[c] + bta[c]);
    }
}

// ---------------------------------------------------------------- GEMM
// 128x128 tile, 4 waves (2x2), 64x64/wave, BK=64, global_load_lds width=16,
// XCD-stripe grid swizzle (FETCH 101->45MB verified R6), XOR bank swizzle
// (conflicts=0 verified R4).
// NEW (R7): double-buffered LDS + RAW s_barrier pipelining (m139 pattern).
// Per iter: wait own DMA (issued a full iter ago) -> raw barrier (no
// compiler vmcnt(0) drain of fresh loads) -> issue next tile into other
// buffer -> ds_read + 32 MFMA on current. Loads fly across compute.
template <int GELU, int RESID, int OUTF32, int VSPLIT>
__global__ __launch_bounds__(256) void gemm_k(
        const u16* __restrict__ A, const u16* __restrict__ Bt,
        const float* __restrict__ bias, const float* __restrict__ resid,
        void* __restrict__ Cv, u16* __restrict__ vt,
        int M, int N, int K, int ldc) {
    __shared__ u16 As[2 * 128 * 64];
    __shared__ u16 Bs[2 * 128 * 64];
    int tid = threadIdx.x;
    int w = tid >> 6, lane = tid & 63;
    int qd = lane >> 4, l15 = lane & 15;

    int lin = blockIdx.x;
    int xcd = lin & 7, idx = lin >> 3;
    int m0 = (xcd * 4 + (idx & 3)) * 128;      // y: XCD-local A stripe
    int n0 = (idx >> 2) * 128;                 // x

    // Staging: 32 chunks of 1 KiB (8 rows x 64 cols bf16); wave w owns 8.
    const u16* gsrc[8];
    u16* ldst[8];
#pragma unroll
    for (int i = 0; i < 8; ++i) {
        int c = w * 8 + i;                     // 0..31; 0-15 = A, 16-31 = B
        int cb = c & 15;
        int row = cb * 8 + (lane >> 3);
        int cg = (lane & 7) ^ (row & 7);       // XOR swizzle, global side
        gsrc[i] = (c < 16 ? A + (size_t)(m0 + row) * K
                          : Bt + (size_t)(n0 + row) * K) + cg * 8;
        ldst[i] = (c < 16 ? As : Bs) + cb * 512;
    }

    int wm = w & 1, wn = w >> 1;
    f32x4 acc[4][4];
#pragma unroll
    for (int mt = 0; mt < 4; ++mt)
#pragma unroll
        for (int nt = 0; nt < 4; ++nt)
            acc[mt][nt] = (f32x4){0.f, 0.f, 0.f, 0.f};

    int aoff[4][2], boff[4][2];
#pragma unroll
    for (int t = 0; t < 4; ++t) {
        int ar = wm * 64 + t * 16 + l15;
        int br = wn * 64 + t * 16 + l15;
#pragma unroll
        for (int h = 0; h < 2; ++h) {
            aoff[t][h] = ar * 64 + (((h * 4 + qd) ^ (ar & 7)) * 8);
            boff[t][h] = br * 64 + (((h * 4 + qd) ^ (br & 7)) * 8);
        }
    }

    // prologue: stage step 0 into buffer 0
#pragma unroll
    for (int i = 0; i < 8; ++i)
        __builtin_amdgcn_global_load_lds(
            (__attribute__((address_space(1))) void*)(gsrc[i]),
            (__attribute__((address_space(3))) void*)(ldst[i]), 16, 0, 0);

    int nsteps = K >> 6;
    for (int s = 0; s < nsteps; ++s) {
        int cur = s & 1;
        WAIT_VMCNT0();                         // my cur-buffer DMA done
        __builtin_amdgcn_s_barrier();          // raw: all waves done staging
                                               // cur & done reading other
        if (s + 1 < nsteps) {                  // wave-uniform branch
            int k0 = (s + 1) << 6;
            int boffs = (cur ^ 1) * 8192;
#pragma unroll
            for (int i = 0; i < 8; ++i)
                __builtin_amdgcn_global_load_lds(
                    (__attribute__((address_space(1))) void*)(gsrc[i] + k0),
                    (__attribute__((address_space(3))) void*)(ldst[i] + boffs),
                    16, 0, 0);
        }
        int off = cur * 8192;
        bf16x8 av[4][2], bv[4][2];
#pragma unroll
        for (int t = 0; t < 4; ++t)
#pragma unroll
            for (int h = 0; h < 2; ++h) {
                av[t][h] = *(const bf16x8*)&As[aoff[t][h] + off];
                bv[t][h] = *(const bf16x8*)&Bs[boff[t][h] + off];
            }
#pragma unroll
        for (int mt = 0; mt < 4; ++mt)
#pragma unroll
            for (int nt = 0; nt < 4; ++nt) {
                acc[mt][nt] = __builtin_amdgcn_mfma_f32_16x16x32_bf16(
                    av[mt][0], bv[nt][0], acc[mt][nt], 0, 0, 0);
                acc[mt][nt] = __builtin_amdgcn_mfma_f32_16x16x32_bf16(
                    av[mt][1], bv[nt][1], acc[mt][nt], 0, 0, 0);
            }
    }

#pragma unroll
    for (int mt = 0; mt < 4; ++mt) {
        int row0 = m0 + wm * 64 + mt * 16 + qd * 4;
#pragma unroll
        for (int nt = 0; nt < 4; ++nt) {
            int col = n0 + wn * 64 + nt * 16 + l15;
            float v[4];
#pragma unroll
            for (int reg = 0; reg < 4; ++reg) {
                v[reg] = acc[mt][nt][reg] + bias[col];
                if (GELU) v[reg] = 0.5f * v[reg] * (1.f + erff(v[reg] * 0.70710678118654752f));
                if (RESID) v[reg] += resid[(size_t)(row0 + reg) * ldc + col];
            }
            if (VSPLIT && col >= 2 * D_MODEL) {
                int d = col - 2 * D_MODEL;
                int bh = (row0 >> 11) * NH + (d >> 6);
                ushort4 pkv = {f2b(v[0]), f2b(v[1]), f2b(v[2]), f2b(v[3])};
                *(ushort4*)&vt[((size_t)(bh * DH + (d & 63))) * SEQ + (row0 & (SEQ - 1))] = pkv;
            } else {
#pragma unroll
                for (int reg = 0; reg < 4; ++reg) {
                    if (OUTF32) ((float*)Cv)[(size_t)(row0 + reg) * ldc + col] = v[reg];
                    else        ((u16*)Cv)[(size_t)(row0 + reg) * ldc + col] = f2b(v[reg]);
                }
            }
        }
    }
}

// ---------------------------------------------------------------- attention
// Flash-style MFMA; one wave per 16-query tile; <=5 chunks of 32 keys.
// qk buffer layout (bf16): [b, s, {q:0..1023, k:1024..2047}]
__global__ __launch_bounds__(256) void attn_k(
        const u16* __restrict__ qk, const u16* __restrict__ vt,
        u16* __restrict__ ctx) {
    int lane = threadIdx.x & 63, l15 = lane & 15, quad = lane >> 4;
    int t = blockIdx.x * 4 + (threadIdx.x >> 6);
    int qt = t & (SEQ / 16 - 1);
    int h  = (t >> 7) & (NH - 1);
    int b  = t >> 11;
    int q0 = qt * 16;
    int bh = b * NH + h;

    const u16* qrow = qk + (size_t)(b * SEQ + q0 + l15) * (2 * D_MODEL) + h * DH + quad * 8;
    bf16x8 qf0 = *(const bf16x8*)(qrow);
    bf16x8 qf1 = *(const bf16x8*)(qrow + 32);
    const u16* kbase = qk + (size_t)(b * SEQ) * (2 * D_MODEL) + D_MODEL + h * DH + quad * 8;
    const u16* vbase = vt + (size_t)(bh * DH) * SEQ;

    f32x4 o[4] = {{0.f, 0.f, 0.f, 0.f}, {0.f, 0.f, 0.f, 0.f},
                  {0.f, 0.f, 0.f, 0.f}, {0.f, 0.f, 0.f, 0.f}};
    float m = -1e30f, l = 0.f;
    int q = q0 + l15;
    int cs = q0 - (WIN - 1);
    cs = cs < 0 ? 0 : (cs & ~31);

    for (int c = cs; c <= q0 + 15; c += 32) {
        const u16* k0p = kbase + (size_t)(c + l15) * (2 * D_MODEL);
        const u16* k1p = k0p + (size_t)16 * (2 * D_MODEL);
        bf16x8 ka0 = *(const bf16x8*)(k0p);
        bf16x8 ka1 = *(const bf16x8*)(k0p + 32);
        bf16x8 kb0 = *(const bf16x8*)(k1p);
        bf16x8 kb1 = *(const bf16x8*)(k1p + 32);
        f32x4 s0 = {0.f, 0.f, 0.f, 0.f}, s1 = {0.f, 0.f, 0.f, 0.f};
        s0 = __builtin_amdgcn_mfma_f32_16x16x32_bf16(ka0, qf0, s0, 0, 0, 0);
        s0 = __builtin_amdgcn_mfma_f32_16x16x32_bf16(ka1, qf1, s0, 0, 0, 0);
        s1 = __builtin_amdgcn_mfma_f32_16x16x32_bf16(kb0, qf0, s1, 0, 0, 0);
        s1 = __builtin_amdgcn_mfma_f32_16x16x32_bf16(kb1, qf1, s1, 0, 0, 0);

        float p0[4], p1[4];
        float cm = -1e30f;
#pragma unroll
        for (int reg = 0; reg < 4; ++reg) {
            int k0i = c + quad * 4 + reg;
            p0[reg] = ((unsigned)(q - k0i) < WIN) ? s0[reg] * 0.125f : -1e30f;
            p1[reg] = ((unsigned)(q - k0i - 16) < WIN) ? s1[reg] * 0.125f : -1e30f;
            cm = fmaxf(cm, fmaxf(p0[reg], p1[reg]));
        }
        cm = fmaxf(cm, __shfl_xor(cm, 16, 64));
        cm = fmaxf(cm, __shfl_xor(cm, 32, 64));
        float mn = fmaxf(m, cm);
        float alpha = __expf(m - mn);
        m = mn;
        float ls = 0.f;
#pragma unroll
        for (int reg = 0; reg < 4; ++reg) {
            p0[reg] = __expf(p0[reg] - mn);
            p1[reg] = __expf(p1[reg] - mn);
            ls += p0[reg] + p1[reg];
        }
        ls += __shfl_xor(ls, 16, 64);
        ls += __shfl_xor(ls, 32, 64);
        l = l * alpha + ls;
#pragma unroll
        for (int mt = 0; mt < 4; ++mt) o[mt] *= alpha;

        u32 z0 = pk2(p0[0], p0[1]), z1 = pk2(p0[2], p0[3]);
        u32 w0 = pk2(p1[0], p1[1]), w1 = pk2(p1[2], p1[3]);
        int slo = ((quad & 1) * 2) * 16 + l15;
        int shi = slo + 16;
        u32 zl0 = (u32)__shfl((int)z0, slo, 64), zl1 = (u32)__shfl((int)z1, slo, 64);
        u32 zh0 = (u32)__shfl((int)z0, shi, 64), zh1 = (u32)__shfl((int)z1, shi, 64);
        u32 wl0 = (u32)__shfl((int)w0, slo, 64), wl1 = (u32)__shfl((int)w1, slo, 64);
        u32 wh0 = (u32)__shfl((int)w0, shi, 64), wh1 = (u32)__shfl((int)w1, shi, 64);
        alignas(16) u32 pr[4];
        pr[0] = quad < 2 ? zl0 : wl0;
        pr[1] = quad < 2 ? zl1 : wl1;
        pr[2] = quad < 2 ? zh0 : wh0;
        pr[3] = quad < 2 ? zh1 : wh1;
        bf16x8 pf = *(const bf16x8*)pr;

#pragma unroll
        for (int mt = 0; mt < 4; ++mt) {
            bf16x8 vf = *(const bf16x8*)(vbase + (size_t)(mt * 16 + l15) * SEQ + c + quad * 8);
            o[mt] = __builtin_amdgcn_mfma_f32_16x16x32_bf16(vf, pf, o[mt], 0, 0, 0);
        }
    }

    float rdiv = 1.f / l;
    u16* crow = ctx + (size_t)(b * SEQ + q0 + l15) * D_MODEL + h * DH;
#pragma unroll
    for (int mt = 0; mt < 4; ++mt) {
        ushort4 pkv = {f2b(o[mt][0] * rdiv), f2b(o[mt][1] * rdiv),
                       f2b(o[mt][2] * rdiv), f2b(o[mt][3] * rdiv)};
        *(ushort4*)(crow + mt * 16 + quad * 4) = pkv;
    }
}

// ---------------------------------------------------------------- launch
extern "C" void kernel_launch(void* const* d_in, const int* in_sizes, int n_in,
                              void* d_out, int out_size, void* d_ws, size_t ws_size,
                              hipStream_t stream) {
    (void)in_sizes; (void)n_in; (void)out_size; (void)ws_size;
    const float* x     = (const float*)d_in[0];
    const float* w_qkv = (const float*)d_in[1];
    const float* b_qkv = (const float*)d_in[2];
    const float* w_out = (const float*)d_in[3];
    const float* b_out = (const float*)d_in[4];
    const float* w_ff1 = (const float*)d_in[5];
    const float* b_ff1 = (const float*)d_in[6];
    const float* w_ff2 = (const float*)d_in[7];
    const float* b_ff2 = (const float*)d_in[8];
    const float* ln1g  = (const float*)d_in[9];
    const float* ln1b  = (const float*)d_in[10];
    const float* ln2g  = (const float*)d_in[11];
    const float* ln2b  = (const float*)d_in[12];
    float* out = (float*)d_out;

    const int M = BATCH * SEQ;                       // 4096
    char* base = (char*)d_ws;                        // 76 MiB peak
    u16*   hbf   = (u16*)(base);                     //  8 MiB: LN out
    u16*   qkbuf = (u16*)(base + (8ll  << 20));      // 16 MiB: Q,K [b,s,2048]
    u16*   ctxbf = (u16*)(base + (24ll << 20));      //  8 MiB: attn out
    u16*   vtbuf = (u16*)(base + (32ll << 20));      //  8 MiB: V^T [bh][d][s]
    u16*   ffbf  = (u16*)(base + (8ll  << 20));      // 24 MiB: FF inter (overlays qk+ctx, disjoint lifetime)
    float* x2    = (float*)(base + (40ll << 20));    // 16 MiB: f32 residual
    u16*   wqkvT = (u16*)(base + (56ll << 20));      //  6 MiB
    u16*   woutT = (u16*)(base + (62ll << 20));      //  2 MiB
    u16*   wff1T = (u16*)(base + (64ll << 20));      //  6 MiB
    u16*   wff2T = (u16*)(base + (70ll << 20));      //  6 MiB

    transpose_cvt_k<<<dim3(3 * D_MODEL / 32, D_MODEL / 32), 256, 0, stream>>>(w_qkv, wqkvT, D_MODEL, 3 * D_MODEL);
    transpose_cvt_k<<<dim3(D_MODEL / 32, D_MODEL / 32), 256, 0, stream>>>(w_out, woutT, D_MODEL, D_MODEL);
    transpose_cvt_k<<<dim3(DFF / 32, D_MODEL / 32), 256, 0, stream>>>(w_ff1, wff1T, D_MODEL, DFF);
    transpose_cvt_k<<<dim3(D_MODEL / 32, DFF / 32), 256, 0, stream>>>(w_ff2, wff2T, DFF, D_MODEL);

    // hbf = bf16(LN1(x))
    ln_k<<<M, 256, 0, stream>>>(x, ln1g, ln1b, hbf);
    // QKV: Q,K -> qkbuf (ldc 2048); V -> vtbuf transposed
    gemm_k<0, 0, 0, 1><<<dim3((3 * D_MODEL / 128) * 32), 256, 0, stream>>>(
        hbf, wqkvT, b_qkv, nullptr, qkbuf, vtbuf, M, 3 * D_MODEL, D_MODEL, 2 * D_MODEL);
    attn_k<<<dim3(BATCH * NH * (SEQ / 16) / 4), 256, 0, stream>>>(qkbuf, vtbuf, ctxbf);
    // x2 = x + ctx @ w_out + b_out
    gemm_k<0, 1, 1, 0><<<dim3((D_MODEL / 128) * 32), 256, 0, stream>>>(
        ctxbf, woutT, b_out, x, x2, nullptr, M, D_MODEL, D_MODEL, D_MODEL);
    // hbf = bf16(LN2(x2))
    ln_k<<<M, 256, 0, stream>>>(x2, ln2g, ln2b, hbf);
    // ffbf = bf16(gelu(hbf @ w_ff1 + b_ff1))
    gemm_k<1, 0, 0, 0><<<dim3((DFF / 128) * 32), 256, 0, stream>>>(
        hbf, wff1T, b_ff1, nullptr, ffbf, nullptr, M, DFF, D_MODEL, DFF);
    // out = x2 + ffbf @ w_ff2 + b_ff2
    gemm_k<0, 1, 1, 0><<<dim3((D_MODEL / 128) * 32), 256, 0, stream>>>(
        ffbf, wff2T, b_ff2, x2, out, nullptr, M, D_MODEL, DFF, D_MODEL);
}